// Round 1
// baseline (437.342 us; speedup 1.0000x reference)
//
#include <hip/hip_runtime.h>

#define KDIM 32
#define DDIM 32
#define EPSC 1e-6f

// ---------- helpers ----------
__device__ __forceinline__ void waveReduceAtomic(float v, float* out, float sign) {
    // reduce within 64-lane wave, lane 0 atomically adds sign*v
    #pragma unroll
    for (int o = 32; o > 0; o >>= 1) v += __shfl_down(v, o, 64);
    if ((threadIdx.x & 63) == 0) atomicAdd(out, sign * v);
}

// ---------- K1: column softmax for Z_i and Z_j ----------
__global__ __launch_bounds__(256) void softmax_cols(
    const float* __restrict__ Zi, const float* __restrict__ Zj,
    float* __restrict__ Zi_s, float* __restrict__ Zj_s, int n_i, int n_j)
{
    int t = blockIdx.x * blockDim.x + threadIdx.x;
    const float* src; float* dst; int n, col;
    if (t < n_i)            { src = Zi; dst = Zi_s; n = n_i; col = t; }
    else if (t < n_i + n_j) { src = Zj; dst = Zj_s; n = n_j; col = t - n_i; }
    else return;
    float v[KDIM];
    float mx = -1e30f;
    #pragma unroll
    for (int p = 0; p < KDIM; p++) { v[p] = src[p * n + col]; mx = fmaxf(mx, v[p]); }
    float s = 0.f;
    #pragma unroll
    for (int p = 0; p < KDIM; p++) { v[p] = __expf(v[p] - mx); s += v[p]; }
    float inv = 1.f / s;
    #pragma unroll
    for (int p = 0; p < KDIM; p++) dst[p * n + col] = v[p] * inv;
}

// ---------- K2a: gather sampled columns, compute ZG ----------
__global__ __launch_bounds__(256) void gather_samples(
    const float* __restrict__ Zi_s, const float* __restrict__ Zj_s,
    const float* __restrict__ Gate, const int* __restrict__ si, const int* __restrict__ sj,
    float* __restrict__ Zsamp, float* __restrict__ ZGsamp,
    int n_i, int n_j, int m_i, int m)
{
    int mi = blockIdx.x * blockDim.x + threadIdx.x;
    if (mi >= m) return;
    int node; const float* Zs; int n;
    if (mi < m_i) { node = si[mi];        Zs = Zi_s; n = n_i; }
    else          { node = sj[mi - m_i];  Zs = Zj_s; n = n_j; }
    float z[KDIM];
    #pragma unroll
    for (int p = 0; p < KDIM; p++) {
        z[p] = Zs[p * n + node];
        Zsamp[p * m + mi] = z[p];
    }
    // NOTE: Gate indexed by raw node id (j half NOT offset by n_i) — faithful to reference
    const float* grow = Gate + (size_t)node * KDIM;
    #pragma unroll
    for (int q = 0; q < KDIM; q++) {
        float g = 1.f / (1.f + __expf(-grow[q]));
        ZGsamp[mi * KDIM + q] = z[q] * g;
    }
}

// ---------- K2b: M = Zsamp @ ZGsamp, s = colsum(ZG), AZC = A @ (M / s) ----------
__global__ __launch_bounds__(1024) void compute_azc(
    const float* __restrict__ Zsamp, const float* __restrict__ ZGsamp,
    const float* __restrict__ A, float* __restrict__ AZC, int m)
{
    __shared__ float Zl[32][33], Gl[32][33], Ms[32][33], Ssh[32];
    int q = threadIdx.x, p = threadIdx.y;
    float acc = 0.f, ssum = 0.f;
    for (int m0 = 0; m0 < m; m0 += 32) {
        int mc = m0 + q;
        Zl[p][q] = (mc < m) ? Zsamp[p * m + mc] : 0.f;
        int mr = m0 + p;
        Gl[p][q] = (mr < m) ? ZGsamp[mr * 32 + q] : 0.f;
        __syncthreads();
        #pragma unroll
        for (int j = 0; j < 32; j++) acc = fmaf(Zl[p][j], Gl[j][q], acc);
        if (p == 0) {
            #pragma unroll
            for (int j = 0; j < 32; j++) ssum += Gl[j][q];
        }
        __syncthreads();
    }
    Ms[p][q] = acc;
    if (p == 0) Ssh[q] = ssum;
    __syncthreads();
    float cn = Ms[p][q] / Ssh[q];
    __syncthreads();
    Zl[p][q] = cn;            // Cn[p][q]
    __syncthreads();
    float azc = 0.f;
    #pragma unroll
    for (int j = 0; j < 32; j++) azc = fmaf(A[p * 32 + j], Zl[j][q], azc);
    AZC[p * 32 + q] = azc;    // AZC[dd=p][q]
}

// ---------- K3: X_all = (AZC @ Z_softmax).T for all nodes ----------
__global__ __launch_bounds__(256) void compute_xall(
    const float* __restrict__ AZC,
    const float* __restrict__ Zi_s, const float* __restrict__ Zj_s,
    float* __restrict__ Xi_all, float* __restrict__ Xj_all, int n_i, int n_j)
{
    __shared__ float Al[32][32];    // Al[dd][p]
    int t = threadIdx.x;
    for (int i = t; i < 1024; i += blockDim.x) Al[i >> 5][i & 31] = AZC[i];
    __syncthreads();
    int node = blockIdx.x * blockDim.x + t;
    const float* Zs; float* X; int n, c;
    if (node < n_i)            { Zs = Zi_s; X = Xi_all; n = n_i; c = node; }
    else if (node < n_i + n_j) { Zs = Zj_s; X = Xj_all; n = n_j; c = node - n_i; }
    else return;
    float z[32];
    #pragma unroll
    for (int p = 0; p < 32; p++) z[p] = Zs[p * n + c];
    #pragma unroll
    for (int dd = 0; dd < 32; dd++) {
        float x = 0.f;
        #pragma unroll
        for (int p = 0; p < 32; p++) x = fmaf(Al[dd][p], z[p], x);
        X[(size_t)c * 32 + dd] = x;
    }
}

// ---------- K3b: gather sampled x rows and beta/gamma ----------
__global__ __launch_bounds__(256) void gather_xsamp(
    const float* __restrict__ Xi_all, const float* __restrict__ Xj_all,
    const int* __restrict__ si, const int* __restrict__ sj,
    const float* __restrict__ beta, const float* __restrict__ gamma,
    float* __restrict__ Xi_sm, float* __restrict__ Xj_sm,
    float* __restrict__ bs, float* __restrict__ gs, int m_i, int m_j)
{
    int t = blockIdx.x * blockDim.x + threadIdx.x;
    int a = t >> 5, dd = t & 31;
    if (a < m_i) {
        int node = si[a];
        Xi_sm[a * 32 + dd] = Xi_all[(size_t)node * 32 + dd];
        if (dd == 0) bs[a] = beta[node];
    } else if (a < m_i + m_j) {
        int b = a - m_i;
        int node = sj[b];
        Xj_sm[b * 32 + dd] = Xj_all[(size_t)node * 32 + dd];
        if (dd == 0) gs[b] = gamma[node];
    }
}

// ---------- K4: pairwise sum of exp(bias - dist), subtracted from out ----------
__global__ __launch_bounds__(256) void pairwise(
    const float* __restrict__ Xi_sm, const float* __restrict__ Xj_sm,
    const float* __restrict__ bs, const float* __restrict__ gs,
    int m_i, int m_j, float* __restrict__ out)
{
    __shared__ float XiL[64][33], XjL[64][33];
    __shared__ float bl[64], gl[64];
    int i0 = blockIdx.x * 64, j0 = blockIdx.y * 64;
    int tid = threadIdx.x;
    #pragma unroll
    for (int l = 0; l < 8; l++) {
        int idx = tid + l * 256;
        int row = idx >> 5, dd = idx & 31;
        int gi = i0 + row;
        XiL[row][dd] = (gi < m_i) ? Xi_sm[gi * 32 + dd] : 0.f;
        int gj = j0 + row;
        XjL[row][dd] = (gj < m_j) ? Xj_sm[gj * 32 + dd] : 0.f;
    }
    if (tid < 64) {
        bl[tid] = (i0 + tid < m_i) ? bs[i0 + tid] : 0.f;
        gl[tid] = (j0 + tid < m_j) ? gs[j0 + tid] : 0.f;
    }
    __syncthreads();
    int ti = tid >> 4, tj = tid & 15;  // 16x16 threads, 4x4 pairs each
    float f[4][4] = {};
    #pragma unroll 4
    for (int dd = 0; dd < 32; dd++) {
        float a0 = XiL[ti * 4 + 0][dd] + EPSC;
        float a1 = XiL[ti * 4 + 1][dd] + EPSC;
        float a2 = XiL[ti * 4 + 2][dd] + EPSC;
        float a3 = XiL[ti * 4 + 3][dd] + EPSC;
        float b0 = XjL[tj * 4 + 0][dd];
        float b1 = XjL[tj * 4 + 1][dd];
        float b2 = XjL[tj * 4 + 2][dd];
        float b3 = XjL[tj * 4 + 3][dd];
        float t00;
        t00 = a0 - b0; f[0][0] = fmaf(t00, t00, f[0][0]);
        t00 = a0 - b1; f[0][1] = fmaf(t00, t00, f[0][1]);
        t00 = a0 - b2; f[0][2] = fmaf(t00, t00, f[0][2]);
        t00 = a0 - b3; f[0][3] = fmaf(t00, t00, f[0][3]);
        t00 = a1 - b0; f[1][0] = fmaf(t00, t00, f[1][0]);
        t00 = a1 - b1; f[1][1] = fmaf(t00, t00, f[1][1]);
        t00 = a1 - b2; f[1][2] = fmaf(t00, t00, f[1][2]);
        t00 = a1 - b3; f[1][3] = fmaf(t00, t00, f[1][3]);
        t00 = a2 - b0; f[2][0] = fmaf(t00, t00, f[2][0]);
        t00 = a2 - b1; f[2][1] = fmaf(t00, t00, f[2][1]);
        t00 = a2 - b2; f[2][2] = fmaf(t00, t00, f[2][2]);
        t00 = a2 - b3; f[2][3] = fmaf(t00, t00, f[2][3]);
        t00 = a3 - b0; f[3][0] = fmaf(t00, t00, f[3][0]);
        t00 = a3 - b1; f[3][1] = fmaf(t00, t00, f[3][1]);
        t00 = a3 - b2; f[3][2] = fmaf(t00, t00, f[3][2]);
        t00 = a3 - b3; f[3][3] = fmaf(t00, t00, f[3][3]);
    }
    float part = 0.f;
    int ib = i0 + ti * 4, jb = j0 + tj * 4;
    #pragma unroll
    for (int r = 0; r < 4; r++) {
        #pragma unroll
        for (int c = 0; c < 4; c++) {
            if (ib + r < m_i && jb + c < m_j) {
                float dist = sqrtf(f[r][c]);
                part += __expf(bl[ti * 4 + r] + gl[tj * 4 + c] - dist);
            }
        }
    }
    waveReduceAtomic(part, out, -1.f);
}

// ---------- K5: edge (link) term, added to out ----------
__global__ __launch_bounds__(256) void edge_term(
    const float* __restrict__ Xi_all, const float* __restrict__ Xj_all,
    const int* __restrict__ ei, const int* __restrict__ ej,
    const float* __restrict__ beta, const float* __restrict__ gamma,
    int E, float* __restrict__ out)
{
    int t = blockIdx.x * blockDim.x + threadIdx.x;
    float part = 0.f;
    if (t < E) {
        int a = ei[t], b = ej[t];
        const float4* xa = (const float4*)(Xi_all + (size_t)a * 32);
        const float4* xb = (const float4*)(Xj_all + (size_t)b * 32);
        float s = 0.f;
        #pragma unroll
        for (int q = 0; q < 8; q++) {
            float4 va = xa[q], vb = xb[q];
            float t0;
            t0 = va.x - vb.x + EPSC; s = fmaf(t0, t0, s);
            t0 = va.y - vb.y + EPSC; s = fmaf(t0, t0, s);
            t0 = va.z - vb.z + EPSC; s = fmaf(t0, t0, s);
            t0 = va.w - vb.w + EPSC; s = fmaf(t0, t0, s);
        }
        part = beta[a] + gamma[b] - sqrtf(s);
    }
    waveReduceAtomic(part, out, 1.f);
}

extern "C" void kernel_launch(void* const* d_in, const int* in_sizes, int n_in,
                              void* d_out, int out_size, void* d_ws, size_t ws_size,
                              hipStream_t stream) {
    const float* beta  = (const float*)d_in[0];
    const float* gamma = (const float*)d_in[1];
    const float* A     = (const float*)d_in[2];
    const float* Z_i   = (const float*)d_in[3];
    const float* Z_j   = (const float*)d_in[4];
    const float* Gate  = (const float*)d_in[5];
    const int*   si    = (const int*)d_in[6];
    const int*   sj    = (const int*)d_in[7];
    const int*   sei   = (const int*)d_in[8];
    const int*   sej   = (const int*)d_in[9];

    int n_i = in_sizes[0], n_j = in_sizes[1];
    int m_i = in_sizes[6], m_j = in_sizes[7], E = in_sizes[8];
    int m = m_i + m_j;
    int nTot = n_i + n_j;

    float* ws = (float*)d_ws;
    float* Zi_s   = ws; ws += (size_t)KDIM * n_i;
    float* Zj_s   = ws; ws += (size_t)KDIM * n_j;
    float* Zsamp  = ws; ws += (size_t)KDIM * m;
    float* ZGsamp = ws; ws += (size_t)m * KDIM;
    float* AZC    = ws; ws += KDIM * KDIM;
    float* Xi_all = ws; ws += (size_t)n_i * KDIM;
    float* Xj_all = ws; ws += (size_t)n_j * KDIM;
    float* Xi_sm  = ws; ws += (size_t)m_i * KDIM;
    float* Xj_sm  = ws; ws += (size_t)m_j * KDIM;
    float* bs     = ws; ws += m_i;
    float* gs     = ws; ws += m_j;

    float* out = (float*)d_out;
    hipMemsetAsync(out, 0, sizeof(float), stream);

    softmax_cols<<<(nTot + 255) / 256, 256, 0, stream>>>(Z_i, Z_j, Zi_s, Zj_s, n_i, n_j);
    gather_samples<<<(m + 255) / 256, 256, 0, stream>>>(Zi_s, Zj_s, Gate, si, sj,
                                                        Zsamp, ZGsamp, n_i, n_j, m_i, m);
    compute_azc<<<1, dim3(32, 32), 0, stream>>>(Zsamp, ZGsamp, A, AZC, m);
    compute_xall<<<(nTot + 255) / 256, 256, 0, stream>>>(AZC, Zi_s, Zj_s, Xi_all, Xj_all, n_i, n_j);
    gather_xsamp<<<((size_t)m * 32 + 255) / 256, 256, 0, stream>>>(Xi_all, Xj_all, si, sj, beta, gamma,
                                                                   Xi_sm, Xj_sm, bs, gs, m_i, m_j);
    dim3 g4((m_i + 63) / 64, (m_j + 63) / 64);
    pairwise<<<g4, 256, 0, stream>>>(Xi_sm, Xj_sm, bs, gs, m_i, m_j, out);
    edge_term<<<(E + 255) / 256, 256, 0, stream>>>(Xi_all, Xj_all, sei, sej, beta, gamma, E, out);
}

// Round 2
// 72.318 us; speedup vs baseline: 6.0475x; 6.0475x over previous
//
#include <hip/hip_runtime.h>

#define KDIM 32
#define EPSC 1e-6f
#define NSLOTS 2048

// ---------- helpers ----------
__device__ __forceinline__ void waveReduceSlot(float v, float* slots, float sign, int waveId) {
    #pragma unroll
    for (int o = 32; o > 0; o >>= 1) v += __shfl_down(v, o, 64);
    if ((threadIdx.x & 63) == 0) atomicAdd(&slots[waveId & (NSLOTS - 1)], sign * v);
}

// ---------- K1: column softmax for Z_i and Z_j ----------
__global__ __launch_bounds__(256) void softmax_cols(
    const float* __restrict__ Zi, const float* __restrict__ Zj,
    float* __restrict__ Zi_s, float* __restrict__ Zj_s, int n_i, int n_j)
{
    int t = blockIdx.x * blockDim.x + threadIdx.x;
    const float* src; float* dst; int n, col;
    if (t < n_i)            { src = Zi; dst = Zi_s; n = n_i; col = t; }
    else if (t < n_i + n_j) { src = Zj; dst = Zj_s; n = n_j; col = t - n_i; }
    else return;
    float v[KDIM];
    float mx = -1e30f;
    #pragma unroll
    for (int p = 0; p < KDIM; p++) { v[p] = src[p * n + col]; mx = fmaxf(mx, v[p]); }
    float s = 0.f;
    #pragma unroll
    for (int p = 0; p < KDIM; p++) { v[p] = __expf(v[p] - mx); s += v[p]; }
    float inv = 1.f / s;
    #pragma unroll
    for (int p = 0; p < KDIM; p++) dst[p * n + col] = v[p] * inv;
}

// ---------- K2: fused gather + partial M/s reduction (multi-block) ----------
// M[p][q] = sum_mi Z[p][node_mi] * (Z[q][node_mi] * sigmoid(Gate[node_mi][q]))
// s[q]    = sum_mi  Z[q][node_mi] * sigmoid(Gate[node_mi][q])
__global__ __launch_bounds__(1024) void gather_reduce_M(
    const float* __restrict__ Zi_s, const float* __restrict__ Zj_s,
    const float* __restrict__ Gate,
    const int* __restrict__ si, const int* __restrict__ sj,
    float* __restrict__ Macc, float* __restrict__ Sacc,
    int n_i, int n_j, int m_i, int m)
{
    __shared__ float Zl[32][33], Gl[32][33];
    __shared__ int nodeL[32];
    int q = threadIdx.x, p = threadIdx.y;
    int m0 = blockIdx.x * 32;
    if (p == 0) {
        int mi = m0 + q;
        int node = -1;
        if (mi < m) node = (mi < m_i) ? si[mi] : sj[mi - m_i];
        nodeL[q] = node;
    }
    __syncthreads();
    // Zl[p][q] = softmaxed Z[p][node of sample q]
    int nq = nodeL[q];
    float zv = 0.f;
    if (nq >= 0) {
        int mi = m0 + q;
        const float* Zs = (mi < m_i) ? Zi_s : Zj_s;
        int n = (mi < m_i) ? n_i : n_j;
        zv = Zs[p * n + nq];
    }
    Zl[p][q] = zv;
    __syncthreads();
    // Gl[p][q] = z_sample_p[q] * sigmoid(Gate[node_p][q])   (raw node id, faithful to ref)
    int np_ = nodeL[p];
    float gv = 0.f;
    if (np_ >= 0) {
        float g = 1.f / (1.f + __expf(-Gate[(size_t)np_ * KDIM + q]));
        gv = Zl[q][p] * g;
    }
    Gl[p][q] = gv;
    __syncthreads();
    float acc = 0.f;
    #pragma unroll
    for (int s = 0; s < 32; s++) acc = fmaf(Zl[p][s], Gl[s][q], acc);
    atomicAdd(&Macc[p * 32 + q], acc);
    if (p == 0) {
        float ss = 0.f;
        #pragma unroll
        for (int s = 0; s < 32; s++) ss += Gl[s][q];
        atomicAdd(&Sacc[q], ss);
    }
}

// ---------- K2b: AZC = A @ (M / s) ----------
__global__ __launch_bounds__(1024) void azc_final(
    const float* __restrict__ Macc, const float* __restrict__ Sacc,
    const float* __restrict__ A, float* __restrict__ AZC)
{
    __shared__ float Cn[32][33];
    int q = threadIdx.x, p = threadIdx.y;
    Cn[p][q] = Macc[p * 32 + q] / Sacc[q];
    __syncthreads();
    float azc = 0.f;
    #pragma unroll
    for (int j = 0; j < 32; j++) azc = fmaf(A[p * 32 + j], Cn[j][q], azc);
    AZC[p * 32 + q] = azc;   // AZC[d=p][q]
}

// ---------- K3: X_all = (AZC @ Z_softmax).T for all nodes ----------
__global__ __launch_bounds__(256) void compute_xall(
    const float* __restrict__ AZC,
    const float* __restrict__ Zi_s, const float* __restrict__ Zj_s,
    float* __restrict__ Xi_all, float* __restrict__ Xj_all, int n_i, int n_j)
{
    __shared__ float Al[32][32];    // Al[d][p]
    int t = threadIdx.x;
    for (int i = t; i < 1024; i += blockDim.x) Al[i >> 5][i & 31] = AZC[i];
    __syncthreads();
    int node = blockIdx.x * blockDim.x + t;
    const float* Zs; float* X; int n, c;
    if (node < n_i)            { Zs = Zi_s; X = Xi_all; n = n_i; c = node; }
    else if (node < n_i + n_j) { Zs = Zj_s; X = Xj_all; n = n_j; c = node - n_i; }
    else return;
    float z[32];
    #pragma unroll
    for (int p = 0; p < 32; p++) z[p] = Zs[p * n + c];
    #pragma unroll
    for (int dd = 0; dd < 32; dd++) {
        float x = 0.f;
        #pragma unroll
        for (int p = 0; p < 32; p++) x = fmaf(Al[dd][p], z[p], x);
        X[(size_t)c * 32 + dd] = x;
    }
}

// ---------- K3b: gather sampled x rows and beta/gamma ----------
__global__ __launch_bounds__(256) void gather_xsamp(
    const float* __restrict__ Xi_all, const float* __restrict__ Xj_all,
    const int* __restrict__ si, const int* __restrict__ sj,
    const float* __restrict__ beta, const float* __restrict__ gamma,
    float* __restrict__ Xi_sm, float* __restrict__ Xj_sm,
    float* __restrict__ bs, float* __restrict__ gs, int m_i, int m_j)
{
    int t = blockIdx.x * blockDim.x + threadIdx.x;
    int a = t >> 5, dd = t & 31;
    if (a < m_i) {
        int node = si[a];
        Xi_sm[a * 32 + dd] = Xi_all[(size_t)node * 32 + dd];
        if (dd == 0) bs[a] = beta[node];
    } else if (a < m_i + m_j) {
        int b = a - m_i;
        int node = sj[b];
        Xj_sm[b * 32 + dd] = Xj_all[(size_t)node * 32 + dd];
        if (dd == 0) gs[b] = gamma[node];
    }
}

// ---------- K4: pairwise sum of exp(bias - dist) -> negative partial slots ----------
__global__ __launch_bounds__(256) void pairwise(
    const float* __restrict__ Xi_sm, const float* __restrict__ Xj_sm,
    const float* __restrict__ bs, const float* __restrict__ gs,
    int m_i, int m_j, float* __restrict__ slots)
{
    __shared__ float XiL[64][33], XjL[64][33];
    __shared__ float bl[64], gl[64];
    int i0 = blockIdx.x * 64, j0 = blockIdx.y * 64;
    int tid = threadIdx.x;
    #pragma unroll
    for (int l = 0; l < 8; l++) {
        int idx = tid + l * 256;
        int row = idx >> 5, dd = idx & 31;
        int gi = i0 + row;
        XiL[row][dd] = (gi < m_i) ? Xi_sm[gi * 32 + dd] : 0.f;
        int gj = j0 + row;
        XjL[row][dd] = (gj < m_j) ? Xj_sm[gj * 32 + dd] : 0.f;
    }
    if (tid < 64) {
        bl[tid] = (i0 + tid < m_i) ? bs[i0 + tid] : 0.f;
        gl[tid] = (j0 + tid < m_j) ? gs[j0 + tid] : 0.f;
    }
    __syncthreads();
    int ti = tid >> 4, tj = tid & 15;  // 16x16 threads, 4x4 pairs each
    float f[4][4] = {};
    #pragma unroll 4
    for (int dd = 0; dd < 32; dd++) {
        float a0 = XiL[ti * 4 + 0][dd] + EPSC;
        float a1 = XiL[ti * 4 + 1][dd] + EPSC;
        float a2 = XiL[ti * 4 + 2][dd] + EPSC;
        float a3 = XiL[ti * 4 + 3][dd] + EPSC;
        float b0 = XjL[tj * 4 + 0][dd];
        float b1 = XjL[tj * 4 + 1][dd];
        float b2 = XjL[tj * 4 + 2][dd];
        float b3 = XjL[tj * 4 + 3][dd];
        float t00;
        t00 = a0 - b0; f[0][0] = fmaf(t00, t00, f[0][0]);
        t00 = a0 - b1; f[0][1] = fmaf(t00, t00, f[0][1]);
        t00 = a0 - b2; f[0][2] = fmaf(t00, t00, f[0][2]);
        t00 = a0 - b3; f[0][3] = fmaf(t00, t00, f[0][3]);
        t00 = a1 - b0; f[1][0] = fmaf(t00, t00, f[1][0]);
        t00 = a1 - b1; f[1][1] = fmaf(t00, t00, f[1][1]);
        t00 = a1 - b2; f[1][2] = fmaf(t00, t00, f[1][2]);
        t00 = a1 - b3; f[1][3] = fmaf(t00, t00, f[1][3]);
        t00 = a2 - b0; f[2][0] = fmaf(t00, t00, f[2][0]);
        t00 = a2 - b1; f[2][1] = fmaf(t00, t00, f[2][1]);
        t00 = a2 - b2; f[2][2] = fmaf(t00, t00, f[2][2]);
        t00 = a2 - b3; f[2][3] = fmaf(t00, t00, f[2][3]);
        t00 = a3 - b0; f[3][0] = fmaf(t00, t00, f[3][0]);
        t00 = a3 - b1; f[3][1] = fmaf(t00, t00, f[3][1]);
        t00 = a3 - b2; f[3][2] = fmaf(t00, t00, f[3][2]);
        t00 = a3 - b3; f[3][3] = fmaf(t00, t00, f[3][3]);
    }
    float part = 0.f;
    int ib = i0 + ti * 4, jb = j0 + tj * 4;
    #pragma unroll
    for (int r = 0; r < 4; r++) {
        #pragma unroll
        for (int c = 0; c < 4; c++) {
            if (ib + r < m_i && jb + c < m_j) {
                float dist = sqrtf(f[r][c]);
                part += __expf(bl[ti * 4 + r] + gl[tj * 4 + c] - dist);
            }
        }
    }
    int waveId = (blockIdx.y * gridDim.x + blockIdx.x) * 4 + (tid >> 6);
    waveReduceSlot(part, slots, -1.f, waveId);
}

// ---------- K5: edge (link) term -> positive partial slots ----------
__global__ __launch_bounds__(256) void edge_term(
    const float* __restrict__ Xi_all, const float* __restrict__ Xj_all,
    const int* __restrict__ ei, const int* __restrict__ ej,
    const float* __restrict__ beta, const float* __restrict__ gamma,
    int E, float* __restrict__ slots)
{
    int t = blockIdx.x * blockDim.x + threadIdx.x;
    float part = 0.f;
    if (t < E) {
        int a = ei[t], b = ej[t];
        const float4* xa = (const float4*)(Xi_all + (size_t)a * 32);
        const float4* xb = (const float4*)(Xj_all + (size_t)b * 32);
        float s = 0.f;
        #pragma unroll
        for (int q = 0; q < 8; q++) {
            float4 va = xa[q], vb = xb[q];
            float t0;
            t0 = va.x - vb.x + EPSC; s = fmaf(t0, t0, s);
            t0 = va.y - vb.y + EPSC; s = fmaf(t0, t0, s);
            t0 = va.z - vb.z + EPSC; s = fmaf(t0, t0, s);
            t0 = va.w - vb.w + EPSC; s = fmaf(t0, t0, s);
        }
        part = beta[a] + gamma[b] - sqrtf(s);
    }
    int waveId = blockIdx.x * 4 + ((threadIdx.x) >> 6);
    waveReduceSlot(part, slots, 1.f, waveId);
}

// ---------- K6: reduce slots -> out[0] ----------
__global__ __launch_bounds__(1024) void final_reduce(const float* __restrict__ slots,
                                                     float* __restrict__ out)
{
    __shared__ float w[16];
    int t = threadIdx.x;
    float v = slots[t] + slots[t + 1024];
    #pragma unroll
    for (int o = 32; o > 0; o >>= 1) v += __shfl_down(v, o, 64);
    if ((t & 63) == 0) w[t >> 6] = v;
    __syncthreads();
    if (t < 64) {
        float x = (t < 16) ? w[t] : 0.f;
        #pragma unroll
        for (int o = 8; o > 0; o >>= 1) x += __shfl_down(x, o, 64);
        if (t == 0) out[0] = x;
    }
}

extern "C" void kernel_launch(void* const* d_in, const int* in_sizes, int n_in,
                              void* d_out, int out_size, void* d_ws, size_t ws_size,
                              hipStream_t stream) {
    const float* beta  = (const float*)d_in[0];
    const float* gamma = (const float*)d_in[1];
    const float* A     = (const float*)d_in[2];
    const float* Z_i   = (const float*)d_in[3];
    const float* Z_j   = (const float*)d_in[4];
    const float* Gate  = (const float*)d_in[5];
    const int*   si    = (const int*)d_in[6];
    const int*   sj    = (const int*)d_in[7];
    const int*   sei   = (const int*)d_in[8];
    const int*   sej   = (const int*)d_in[9];

    int n_i = in_sizes[0], n_j = in_sizes[1];
    int m_i = in_sizes[6], m_j = in_sizes[7], E = in_sizes[8];
    int m = m_i + m_j;
    int nTot = n_i + n_j;

    float* ws = (float*)d_ws;
    // zeroed region first: Macc | Sacc | slots
    float* Macc   = ws; ws += 1024;
    float* Sacc   = ws; ws += 32;
    float* slots  = ws; ws += NSLOTS;
    float* Zi_s   = ws; ws += (size_t)KDIM * n_i;
    float* Zj_s   = ws; ws += (size_t)KDIM * n_j;
    float* AZC    = ws; ws += KDIM * KDIM;
    float* Xi_all = ws; ws += (size_t)n_i * KDIM;
    float* Xj_all = ws; ws += (size_t)n_j * KDIM;
    float* Xi_sm  = ws; ws += (size_t)m_i * KDIM;
    float* Xj_sm  = ws; ws += (size_t)m_j * KDIM;
    float* bs     = ws; ws += m_i;
    float* gs     = ws; ws += m_j;

    hipMemsetAsync(Macc, 0, (1024 + 32 + NSLOTS) * sizeof(float), stream);

    softmax_cols<<<(nTot + 255) / 256, 256, 0, stream>>>(Z_i, Z_j, Zi_s, Zj_s, n_i, n_j);
    gather_reduce_M<<<(m + 31) / 32, dim3(32, 32), 0, stream>>>(Zi_s, Zj_s, Gate, si, sj,
                                                                Macc, Sacc, n_i, n_j, m_i, m);
    azc_final<<<1, dim3(32, 32), 0, stream>>>(Macc, Sacc, A, AZC);
    compute_xall<<<(nTot + 255) / 256, 256, 0, stream>>>(AZC, Zi_s, Zj_s, Xi_all, Xj_all, n_i, n_j);
    gather_xsamp<<<((size_t)m * 32 + 255) / 256, 256, 0, stream>>>(Xi_all, Xj_all, si, sj, beta, gamma,
                                                                   Xi_sm, Xj_sm, bs, gs, m_i, m_j);
    dim3 g4((m_i + 63) / 64, (m_j + 63) / 64);
    pairwise<<<g4, 256, 0, stream>>>(Xi_sm, Xj_sm, bs, gs, m_i, m_j, slots);
    edge_term<<<(E + 255) / 256, 256, 0, stream>>>(Xi_all, Xj_all, sei, sej, beta, gamma, E, slots);
    final_reduce<<<1, 1024, 0, stream>>>(slots, (float*)d_out);
}

// Round 3
// 69.775 us; speedup vs baseline: 6.2679x; 1.0364x over previous
//
#include <hip/hip_runtime.h>

#define KDIM 32
#define EPSC 1e-6f
#define NSLOTS 2048

// ---------- helpers ----------
__device__ __forceinline__ void waveReduceSlot(float v, float* slots, float sign, int waveId) {
    #pragma unroll
    for (int o = 32; o > 0; o >>= 1) v += __shfl_down(v, o, 64);
    if ((threadIdx.x & 63) == 0) atomicAdd(&slots[waveId & (NSLOTS - 1)], sign * v);
}

// ---------- K1: column softmax for Z_i and Z_j (+ zero the accumulator region) ----------
__global__ __launch_bounds__(256) void softmax_cols(
    const float* __restrict__ Zi, const float* __restrict__ Zj,
    float* __restrict__ Zi_s, float* __restrict__ Zj_s,
    float* __restrict__ zeroRegion, int zeroCount, int n_i, int n_j)
{
    int t = blockIdx.x * blockDim.x + threadIdx.x;
    if (t < zeroCount) zeroRegion[t] = 0.f;   // Macc|Sacc|slots, consumed by later dispatches
    const float* src; float* dst; int n, col;
    if (t < n_i)            { src = Zi; dst = Zi_s; n = n_i; col = t; }
    else if (t < n_i + n_j) { src = Zj; dst = Zj_s; n = n_j; col = t - n_i; }
    else return;
    float v[KDIM];
    float mx = -1e30f;
    #pragma unroll
    for (int p = 0; p < KDIM; p++) { v[p] = src[p * n + col]; mx = fmaxf(mx, v[p]); }
    float s = 0.f;
    #pragma unroll
    for (int p = 0; p < KDIM; p++) { v[p] = __expf(v[p] - mx); s += v[p]; }
    float inv = 1.f / s;
    #pragma unroll
    for (int p = 0; p < KDIM; p++) dst[p * n + col] = v[p] * inv;
}

// ---------- K2: fused gather + partial M/s reduction (multi-block, atomic into Macc/Sacc) ----------
// M[p][q] = sum_mi Z[p][node_mi] * (Z[q][node_mi] * sigmoid(Gate[node_mi][q]))
// s[q]    = sum_mi  Z[q][node_mi] * sigmoid(Gate[node_mi][q])
__global__ __launch_bounds__(1024) void gather_reduce_M(
    const float* __restrict__ Zi_s, const float* __restrict__ Zj_s,
    const float* __restrict__ Gate,
    const int* __restrict__ si, const int* __restrict__ sj,
    float* __restrict__ Macc, float* __restrict__ Sacc,
    int n_i, int n_j, int m_i, int m)
{
    __shared__ float Zl[32][33], Gl[32][33];
    __shared__ int nodeL[32];
    int q = threadIdx.x, p = threadIdx.y;
    int m0 = blockIdx.x * 32;
    if (p == 0) {
        int mi = m0 + q;
        int node = -1;
        if (mi < m) node = (mi < m_i) ? si[mi] : sj[mi - m_i];
        nodeL[q] = node;
    }
    __syncthreads();
    int nq = nodeL[q];
    float zv = 0.f;
    if (nq >= 0) {
        int mi = m0 + q;
        const float* Zs = (mi < m_i) ? Zi_s : Zj_s;
        int n = (mi < m_i) ? n_i : n_j;
        zv = Zs[p * n + nq];
    }
    Zl[p][q] = zv;
    __syncthreads();
    // Gl[p][q] = z_sample_p[q] * sigmoid(Gate[node_p][q])   (raw node id, faithful to ref)
    int np_ = nodeL[p];
    float gv = 0.f;
    if (np_ >= 0) {
        float g = 1.f / (1.f + __expf(-Gate[(size_t)np_ * KDIM + q]));
        gv = Zl[q][p] * g;
    }
    Gl[p][q] = gv;
    __syncthreads();
    float acc = 0.f;
    #pragma unroll
    for (int s = 0; s < 32; s++) acc = fmaf(Zl[p][s], Gl[s][q], acc);
    atomicAdd(&Macc[p * 32 + q], acc);
    if (p == 0) {
        float ss = 0.f;
        #pragma unroll
        for (int s = 0; s < 32; s++) ss += Gl[s][q];
        atomicAdd(&Sacc[q], ss);
    }
}

// ---------- K3: AZC (in-LDS, per block) + X_all = (AZC @ Z_softmax).T ----------
__global__ __launch_bounds__(256) void compute_xall(
    const float* __restrict__ Macc, const float* __restrict__ Sacc,
    const float* __restrict__ A,
    const float* __restrict__ Zi_s, const float* __restrict__ Zj_s,
    float* __restrict__ Xi_all, float* __restrict__ Xj_all, int n_i, int n_j)
{
    __shared__ float Cn[32][33];
    __shared__ float Al[32][32];    // AZC[d][p]
    int t = threadIdx.x;
    for (int idx = t; idx < 1024; idx += 256)
        Cn[idx >> 5][idx & 31] = Macc[idx] / Sacc[idx & 31];
    __syncthreads();
    for (int idx = t; idx < 1024; idx += 256) {
        int d = idx >> 5, q = idx & 31;
        float s = 0.f;
        #pragma unroll
        for (int j = 0; j < 32; j++) s = fmaf(A[d * 32 + j], Cn[j][q], s);
        Al[d][q] = s;
    }
    __syncthreads();
    int node = blockIdx.x * blockDim.x + t;
    const float* Zs; float* X; int n, c;
    if (node < n_i)            { Zs = Zi_s; X = Xi_all; n = n_i; c = node; }
    else if (node < n_i + n_j) { Zs = Zj_s; X = Xj_all; n = n_j; c = node - n_i; }
    else return;
    float z[32];
    #pragma unroll
    for (int p = 0; p < 32; p++) z[p] = Zs[p * n + c];
    #pragma unroll
    for (int dd = 0; dd < 32; dd++) {
        float x = 0.f;
        #pragma unroll
        for (int p = 0; p < 32; p++) x = fmaf(Al[dd][p], z[p], x);
        X[(size_t)c * 32 + dd] = x;
    }
}

// ---------- K4: pairwise sum of exp(bias - dist), gather fused in -> negative slots ----------
__global__ __launch_bounds__(256) void pairwise(
    const float* __restrict__ Xi_all, const float* __restrict__ Xj_all,
    const int* __restrict__ si, const int* __restrict__ sj,
    const float* __restrict__ beta, const float* __restrict__ gamma,
    int m_i, int m_j, float* __restrict__ slots)
{
    __shared__ float XiL[64][33], XjL[64][33];
    __shared__ float bl[64], gl[64];
    int i0 = blockIdx.x * 64, j0 = blockIdx.y * 64;
    int tid = threadIdx.x;
    #pragma unroll
    for (int l = 0; l < 8; l++) {
        int idx = tid + l * 256;
        int row = idx >> 5, dd = idx & 31;
        int gi = i0 + row;
        XiL[row][dd] = (gi < m_i) ? Xi_all[(size_t)si[gi] * 32 + dd] : 0.f;
        int gj = j0 + row;
        XjL[row][dd] = (gj < m_j) ? Xj_all[(size_t)sj[gj] * 32 + dd] : 0.f;
    }
    if (tid < 64) {
        bl[tid] = (i0 + tid < m_i) ? beta[si[i0 + tid]] : 0.f;
        gl[tid] = (j0 + tid < m_j) ? gamma[sj[j0 + tid]] : 0.f;
    }
    __syncthreads();
    int ti = tid >> 4, tj = tid & 15;  // 16x16 threads, 4x4 pairs each
    float f[4][4] = {};
    #pragma unroll 4
    for (int dd = 0; dd < 32; dd++) {
        float a0 = XiL[ti * 4 + 0][dd] + EPSC;
        float a1 = XiL[ti * 4 + 1][dd] + EPSC;
        float a2 = XiL[ti * 4 + 2][dd] + EPSC;
        float a3 = XiL[ti * 4 + 3][dd] + EPSC;
        float b0 = XjL[tj * 4 + 0][dd];
        float b1 = XjL[tj * 4 + 1][dd];
        float b2 = XjL[tj * 4 + 2][dd];
        float b3 = XjL[tj * 4 + 3][dd];
        float t00;
        t00 = a0 - b0; f[0][0] = fmaf(t00, t00, f[0][0]);
        t00 = a0 - b1; f[0][1] = fmaf(t00, t00, f[0][1]);
        t00 = a0 - b2; f[0][2] = fmaf(t00, t00, f[0][2]);
        t00 = a0 - b3; f[0][3] = fmaf(t00, t00, f[0][3]);
        t00 = a1 - b0; f[1][0] = fmaf(t00, t00, f[1][0]);
        t00 = a1 - b1; f[1][1] = fmaf(t00, t00, f[1][1]);
        t00 = a1 - b2; f[1][2] = fmaf(t00, t00, f[1][2]);
        t00 = a1 - b3; f[1][3] = fmaf(t00, t00, f[1][3]);
        t00 = a2 - b0; f[2][0] = fmaf(t00, t00, f[2][0]);
        t00 = a2 - b1; f[2][1] = fmaf(t00, t00, f[2][1]);
        t00 = a2 - b2; f[2][2] = fmaf(t00, t00, f[2][2]);
        t00 = a2 - b3; f[2][3] = fmaf(t00, t00, f[2][3]);
        t00 = a3 - b0; f[3][0] = fmaf(t00, t00, f[3][0]);
        t00 = a3 - b1; f[3][1] = fmaf(t00, t00, f[3][1]);
        t00 = a3 - b2; f[3][2] = fmaf(t00, t00, f[3][2]);
        t00 = a3 - b3; f[3][3] = fmaf(t00, t00, f[3][3]);
    }
    float part = 0.f;
    int ib = i0 + ti * 4, jb = j0 + tj * 4;
    #pragma unroll
    for (int r = 0; r < 4; r++) {
        #pragma unroll
        for (int c = 0; c < 4; c++) {
            if (ib + r < m_i && jb + c < m_j) {
                float dist = sqrtf(f[r][c]);
                part += __expf(bl[ti * 4 + r] + gl[tj * 4 + c] - dist);
            }
        }
    }
    int waveId = (blockIdx.y * gridDim.x + blockIdx.x) * 4 + (tid >> 6);
    waveReduceSlot(part, slots, -1.f, waveId);
}

// ---------- K5: edge (link) term -> positive slots ----------
__global__ __launch_bounds__(256) void edge_term(
    const float* __restrict__ Xi_all, const float* __restrict__ Xj_all,
    const int* __restrict__ ei, const int* __restrict__ ej,
    const float* __restrict__ beta, const float* __restrict__ gamma,
    int E, float* __restrict__ slots)
{
    int t = blockIdx.x * blockDim.x + threadIdx.x;
    float part = 0.f;
    if (t < E) {
        int a = ei[t], b = ej[t];
        const float4* xa = (const float4*)(Xi_all + (size_t)a * 32);
        const float4* xb = (const float4*)(Xj_all + (size_t)b * 32);
        float s = 0.f;
        #pragma unroll
        for (int q = 0; q < 8; q++) {
            float4 va = xa[q], vb = xb[q];
            float t0;
            t0 = va.x - vb.x + EPSC; s = fmaf(t0, t0, s);
            t0 = va.y - vb.y + EPSC; s = fmaf(t0, t0, s);
            t0 = va.z - vb.z + EPSC; s = fmaf(t0, t0, s);
            t0 = va.w - vb.w + EPSC; s = fmaf(t0, t0, s);
        }
        part = beta[a] + gamma[b] - sqrtf(s);
    }
    int waveId = blockIdx.x * 4 + ((threadIdx.x) >> 6);
    waveReduceSlot(part, slots, 1.f, waveId);
}

// ---------- K6: reduce slots -> out[0] ----------
__global__ __launch_bounds__(1024) void final_reduce(const float* __restrict__ slots,
                                                     float* __restrict__ out)
{
    __shared__ float w[16];
    int t = threadIdx.x;
    float v = slots[t] + slots[t + 1024];
    #pragma unroll
    for (int o = 32; o > 0; o >>= 1) v += __shfl_down(v, o, 64);
    if ((t & 63) == 0) w[t >> 6] = v;
    __syncthreads();
    if (t < 64) {
        float x = (t < 16) ? w[t] : 0.f;
        #pragma unroll
        for (int o = 8; o > 0; o >>= 1) x += __shfl_down(x, o, 64);
        if (t == 0) out[0] = x;
    }
}

extern "C" void kernel_launch(void* const* d_in, const int* in_sizes, int n_in,
                              void* d_out, int out_size, void* d_ws, size_t ws_size,
                              hipStream_t stream) {
    const float* beta  = (const float*)d_in[0];
    const float* gamma = (const float*)d_in[1];
    const float* A     = (const float*)d_in[2];
    const float* Z_i   = (const float*)d_in[3];
    const float* Z_j   = (const float*)d_in[4];
    const float* Gate  = (const float*)d_in[5];
    const int*   si    = (const int*)d_in[6];
    const int*   sj    = (const int*)d_in[7];
    const int*   sei   = (const int*)d_in[8];
    const int*   sej   = (const int*)d_in[9];

    int n_i = in_sizes[0], n_j = in_sizes[1];
    int m_i = in_sizes[6], m_j = in_sizes[7], E = in_sizes[8];
    int m = m_i + m_j;
    int nTot = n_i + n_j;

    float* ws = (float*)d_ws;
    // zeroed-by-K1 region first: Macc | Sacc | slots
    float* Macc   = ws; ws += 1024;
    float* Sacc   = ws; ws += 32;
    float* slots  = ws; ws += NSLOTS;
    int zeroCount = 1024 + 32 + NSLOTS;
    float* Zi_s   = ws; ws += (size_t)KDIM * n_i;
    float* Zj_s   = ws; ws += (size_t)KDIM * n_j;
    float* Xi_all = ws; ws += (size_t)n_i * KDIM;
    float* Xj_all = ws; ws += (size_t)n_j * KDIM;

    softmax_cols<<<(nTot + 255) / 256, 256, 0, stream>>>(Z_i, Z_j, Zi_s, Zj_s,
                                                         Macc, zeroCount, n_i, n_j);
    gather_reduce_M<<<(m + 31) / 32, dim3(32, 32), 0, stream>>>(Zi_s, Zj_s, Gate, si, sj,
                                                                Macc, Sacc, n_i, n_j, m_i, m);
    compute_xall<<<(nTot + 255) / 256, 256, 0, stream>>>(Macc, Sacc, A, Zi_s, Zj_s,
                                                         Xi_all, Xj_all, n_i, n_j);
    dim3 g4((m_i + 63) / 64, (m_j + 63) / 64);
    pairwise<<<g4, 256, 0, stream>>>(Xi_all, Xj_all, si, sj, beta, gamma, m_i, m_j, slots);
    edge_term<<<(E + 255) / 256, 256, 0, stream>>>(Xi_all, Xj_all, sei, sej, beta, gamma, E, slots);
    final_reduce<<<1, 1024, 0, stream>>>(slots, (float*)d_out);
}